// Round 5
// baseline (107.246 us; speedup 1.0000x reference)
//
#include <hip/hip_runtime.h>
#include <math.h>

#define B_   8
#define T_   128
#define C_   256
#define XLDP 136       // X/W LDS row stride in ushorts (128 + 8 pad; 272B = odd 16B-granule stride)
#define SLDP 82        // S LDS row stride in ushorts

// LDS regions (overlapping across barrier-separated phases)
#define OFF_WS 34816   // Xs [0, 34816) = 128*136*2 ; Ws 80*136*2 = 21760 -> end 56576
#define OFF_S1 20992   // S0 [0, 20992) = 128*82*2 ; S1 -> end 41984
#define OFF_BV 41984   // Bv f32 [8][3][128] = 12288 -> end 54272
#define OFF_LO 54272   // Lo f32 [128][9] = 4608 -> end 58880
#define SMEMB  58880

typedef unsigned short ushort;
typedef ushort ushort8v __attribute__((ext_vector_type(8)));
typedef __bf16 bf16x8  __attribute__((ext_vector_type(8)));
typedef float  f32x4   __attribute__((ext_vector_type(4)));
typedef float  f32x2   __attribute__((ext_vector_type(2)));

__device__ __forceinline__ ushort f2bf(float f) {
    unsigned u = __float_as_uint(f);
    u += 0x7fffu + ((u >> 16) & 1u);     // RNE
    return (ushort)(u >> 16);
}
__device__ __forceinline__ float bf2f(ushort u) {
    return __uint_as_float((unsigned)u << 16);
}

// gelu ~ x * sigmoid(1.59577x + 0.0713548x^3); __expf = native v_exp_f32 path
__device__ __forceinline__ float gelu_fast(float x) {
    float x2 = x * x;
    float y  = x * fmaf(0.0713548162726f, x2, 1.59576912161f);
    float e  = __expf(-y);
    return x * __builtin_amdgcn_rcpf(1.0f + e);
}

__device__ __forceinline__ ushort8v pack8(float4 lo, float4 hi) {
    ushort8v u;
    u[0] = f2bf(lo.x); u[1] = f2bf(lo.y); u[2] = f2bf(lo.z); u[3] = f2bf(lo.w);
    u[4] = f2bf(hi.x); u[5] = f2bf(hi.y); u[6] = f2bf(hi.z); u[7] = f2bf(hi.w);
    return u;
}

// ---------------------------------------------------------------------------
// Single fused kernel. Block = (b, og): 8 output channels o = og*8..og*8+7.
// Rounds r = (side s = r>>1, k-half p = r&1):
//   stage X_s[b][:, p*128..] and W-slice [o, s*256+p*128.., taps] as bf16 in LDS,
//   GEMM S_s[m][n] += (16x16x32 bf16 MFMA), n = oo*9 + shift*3 + free
//   (side 1's 3x3 tap block transposed in the staging scatter so shift=kw).
// Then: S -> LDS bf16, shift-recombination, gelu-mean, residual writeout.
// ---------------------------------------------------------------------------
__global__ __launch_bounds__(512) void tc_all(
    const float* __restrict__ x1, const float* __restrict__ x2,
    const float* __restrict__ W, const float* __restrict__ bias,
    const float* __restrict__ alpha_p, float* __restrict__ out)
{
    __shared__ __align__(16) char smem[SMEMB];
    ushort* Xs = (ushort*)smem;
    ushort* Ws = (ushort*)(smem + OFF_WS);
    float*  Bv = (float*)(smem + OFF_BV);
    float*  Lo = (float*)(smem + OFF_LO);

    const int u  = threadIdx.x;
    const int b  = blockIdx.x >> 5;
    const int og = blockIdx.x & 31;
    const int l  = u & 63, w = u >> 6;       // wave id 0..7
    const int r16 = l & 15, kb = l >> 4;

    const int xrow = u >> 2, xcb = (u & 3) * 32;
    const size_t xoff  = (size_t)(b * T_ + xrow) * C_ + xcb;
    const size_t wbase = (size_t)og * 8 * 4608;

    f32x4 acc[2][5] = {};
    ushort8v xbuf[2][4];
    ushort   wbuf[2][18];

    // ---- preload round 0 (s=0, p=0)
    {
        const float* xs = x1 + xoff;
        #pragma unroll
        for (int c = 0; c < 4; ++c) {
            float4 lo = *(const float4*)(xs + c * 8);
            float4 hi = *(const float4*)(xs + c * 8 + 4);
            xbuf[0][c] = pack8(lo, hi);
        }
        #pragma unroll
        for (int i = 0; i < 18; ++i) {
            int d = i * 512 + u;
            int oo = d / 1152, e = d - oo * 1152;     // e = kk*9 + r9, contiguous per oo
            wbuf[0][i] = f2bf(W[wbase + (size_t)oo * 4608 + e]);
        }
    }

    #pragma unroll
    for (int r = 0; r < 4; ++r) {
        const int cur = r & 1;
        const int s   = r >> 1;
        __syncthreads();                     // prior round's frag reads done
        // ---- X LDS write
        #pragma unroll
        for (int c = 0; c < 4; ++c)
            *(ushort8v*)&Xs[xrow * XLDP + xcb + c * 8] = xbuf[cur][c];
        // ---- W LDS scatter (side-1: transpose 3x3 tap block so row = kw*3+kh)
        #pragma unroll
        for (int i = 0; i < 18; ++i) {
            int d  = i * 512 + u;
            int oo = d / 1152, e = d - oo * 1152;
            int kk = e / 9,    r9 = e - kk * 9;
            int rd = (s == 0) ? r9 : (r9 % 3) * 3 + (r9 / 3);
            Ws[(oo * 9 + rd) * XLDP + kk] = wbuf[cur][i];
        }
        // ---- prefetch next round
        if (r < 3) {
            const int rn = r + 1, sn = rn >> 1, pn = rn & 1;
            const float* xs = (sn ? x2 : x1) + xoff + pn * 128;
            #pragma unroll
            for (int c = 0; c < 4; ++c) {
                float4 lo = *(const float4*)(xs + c * 8);
                float4 hi = *(const float4*)(xs + c * 8 + 4);
                xbuf[cur ^ 1][c] = pack8(lo, hi);
            }
            const int soff9 = (sn * 256 + pn * 128) * 9;
            #pragma unroll
            for (int i = 0; i < 18; ++i) {
                int d = i * 512 + u;
                int oo = d / 1152, e = d - oo * 1152;
                wbuf[cur ^ 1][i] = f2bf(W[wbase + (size_t)oo * 4608 + soff9 + e]);
            }
        }
        __syncthreads();
        // ---- MFMA: wave w owns m-rows w*16..w*16+15, all 5 n-frags
        #pragma unroll
        for (int ks = 0; ks < 4; ++ks) {
            bf16x8 af = __builtin_bit_cast(bf16x8,
                *(const ushort8v*)&Xs[(w * 16 + r16) * XLDP + ks * 32 + kb * 8]);
            #pragma unroll
            for (int nf = 0; nf < 5; ++nf) {
                bf16x8 bfr = __builtin_bit_cast(bf16x8,
                    *(const ushort8v*)&Ws[(nf * 16 + r16) * XLDP + ks * 32 + kb * 8]);
                acc[s][nf] = __builtin_amdgcn_mfma_f32_16x16x32_bf16(af, bfr, acc[s][nf], 0, 0, 0);
            }
        }
    }
    __syncthreads();                          // all frag reads done; reuse LDS for S

    // ---- write S (bf16): D layout m = w*16 + kb*4 + reg, n = nf*16 + r16
    #pragma unroll
    for (int s = 0; s < 2; ++s) {
        ushort* Sb = (ushort*)(smem + (s ? OFF_S1 : 0));
        #pragma unroll
        for (int nf = 0; nf < 5; ++nf) {
            int n = nf * 16 + r16;
            if (n < 72) {
                #pragma unroll
                for (int reg = 0; reg < 4; ++reg)
                    Sb[(w * 16 + kb * 4 + reg) * SLDP + n] = f2bf(acc[s][nf][reg]);
            }
        }
    }
    __syncthreads();

    // ---- recombination: wave w -> oo = w; thread handles t = l, l+64
    const int oo  = w;
    const int t0  = l;
    const float bo = bias[og * 8 + oo];
    const ushort* S0 = (const ushort*)smem;
    const ushort* S1 = (const ushort*)(smem + OFF_S1);
    float A3[2], Al[2], Ar[2];
    #pragma unroll
    for (int idx = 0; idx < 2; ++idx) {
        int tt = t0 + idx * 64;
        float a0 = 0.f, a1 = 0.f, a2 = 0.f;          // free tap = kw
        #pragma unroll
        for (int sh = 0; sh < 3; ++sh) {             // shift tap = kh (on t1)
            int row = tt + sh - 1;
            if (row >= 0 && row < T_) {
                int base = row * SLDP + oo * 9 + sh * 3;
                a0 += bf2f(S0[base]); a1 += bf2f(S0[base + 1]); a2 += bf2f(S0[base + 2]);
            }
        }
        A3[idx] = bo + a0 + a1 + a2;                 // interior t2
        Al[idx] = bo + a1 + a2;                      // t2 == 0
        Ar[idx] = bo + a0 + a1;                      // t2 == T-1
        float b0 = 0.f, b1 = 0.f, b2 = 0.f;          // free tap = kh
        #pragma unroll
        for (int sh = 0; sh < 3; ++sh) {             // shift tap = kw (on t2)
            int row = tt + sh - 1;
            if (row >= 0 && row < T_) {
                int base = row * SLDP + oo * 9 + sh * 3;
                b0 += bf2f(S1[base]); b1 += bf2f(S1[base + 1]); b2 += bf2f(S1[base + 2]);
            }
        }
        Bv[(oo * 3 + 0) * T_ + tt] = b0 + b1 + b2;   // interior t1
        Bv[(oo * 3 + 1) * T_ + tt] = b1 + b2;        // t1 == 0
        Bv[(oo * 3 + 2) * T_ + tt] = b0 + b1;        // t1 == T-1
    }
    // NOTE: no barrier — Bv rows [oo*3, oo*3+3) are written and read by wave oo only.

    // ---- gelu-mean
    #pragma unroll
    for (int idx = 0; idx < 2; ++idx) {
        int tt  = t0 + idx * 64;
        int cls = (tt == 0) ? 1 : ((tt == T_ - 1) ? 2 : 0);
        const float* Bs = Bv + (oo * 3 + cls) * T_;
        float A = A3[idx];
        float s0 = 0.f, s1 = 0.f, s2 = 0.f, s3 = 0.f;
        for (int j = 0; j < T_; j += 4) {
            f32x4 v = *(const f32x4*)&Bs[j];
            s0 += gelu_fast(A + v[0]); s1 += gelu_fast(A + v[1]);
            s2 += gelu_fast(A + v[2]); s3 += gelu_fast(A + v[3]);
        }
        float sm = (s0 + s1) + (s2 + s3);
        float bl = Bs[0], br = Bs[T_ - 1];
        sm += gelu_fast(Al[idx] + bl) - gelu_fast(A + bl);
        sm += gelu_fast(Ar[idx] + br) - gelu_fast(A + br);
        Lo[tt * 9 + oo] = sm;
    }
    __syncthreads();

    // ---- transposed coalesced writeout with residual
    const float kk2 = (*alpha_p) * (1.0f / (float)T_);
    {
        int row = u >> 2, c2 = (u & 3) * 2;
        size_t go = ((size_t)(b * T_ + row)) * C_ + og * 8 + c2;
        f32x2 rr;
        rr[0] = Lo[row * 9 + c2]     * kk2 + x1[go];
        rr[1] = Lo[row * 9 + c2 + 1] * kk2 + x1[go + 1];
        *(f32x2*)&out[go] = rr;
    }
}

extern "C" void kernel_launch(void* const* d_in, const int* in_sizes, int n_in,
                              void* d_out, int out_size, void* d_ws, size_t ws_size,
                              hipStream_t stream) {
    const float* x1    = (const float*)d_in[0];
    const float* x2    = (const float*)d_in[1];
    const float* W     = (const float*)d_in[2];
    const float* bias  = (const float*)d_in[3];
    const float* alpha = (const float*)d_in[4];
    float* out = (float*)d_out;

    tc_all<<<B_ * 32, 512, 0, stream>>>(x1, x2, W, bias, alpha, out);
}

// Round 6
// 100.426 us; speedup vs baseline: 1.0679x; 1.0679x over previous
//
#include <hip/hip_runtime.h>
#include <math.h>

#define B_   8
#define T_   128
#define C_   256
#define XLDP 136       // X/W LDS row stride in ushorts (128 + 8 pad)
#define SLDW 37        // S LDS row stride in dwords (f32), odd -> conflict-free column reads
#define LOP  5         // Lo row stride in f32

// LDS regions (overlapping across barrier-separated phases)
// GEMM phase:  Xs [0, 34816) = 128*136*2 ; Ws [34816, 34816+48*136*2=13056) -> end 47872
// Post phase:  S0 [0, 18944) = 128*37*4 ; S1 [18944, 37888) ; Bv [37888, 44032) = 4*3*128*4
//              Lo [44032, 46592) = 128*5*4
#define OFF_WS 34816
#define OFF_S1 18944
#define OFF_BV 37888
#define OFF_LO 44032
#define SMEMB  47872

typedef unsigned short ushort;
typedef ushort ushort8v __attribute__((ext_vector_type(8)));
typedef __bf16 bf16x8  __attribute__((ext_vector_type(8)));
typedef float  f32x4   __attribute__((ext_vector_type(4)));

__device__ __forceinline__ ushort f2bf(float f) {
    unsigned u = __float_as_uint(f);
    u += 0x7fffu + ((u >> 16) & 1u);     // RNE
    return (ushort)(u >> 16);
}

// gelu ~ x * sigmoid(1.59577x + 0.0713548x^3); exp2-folded, native v_exp_f32
__device__ __forceinline__ float gelu_fast(float x) {
    float x2 = x * x;
    float y2 = x * fmaf(-0.10294234f, x2, -2.30220818f);  // -y*log2(e)
    float e  = __builtin_amdgcn_exp2f(y2);
    return x * __builtin_amdgcn_rcpf(1.0f + e);
}

__device__ __forceinline__ ushort8v pack8(float4 lo, float4 hi) {
    ushort8v u;
    u[0] = f2bf(lo.x); u[1] = f2bf(lo.y); u[2] = f2bf(lo.z); u[3] = f2bf(lo.w);
    u[4] = f2bf(hi.x); u[5] = f2bf(hi.y); u[6] = f2bf(hi.z); u[7] = f2bf(hi.w);
    return u;
}

// ---------------------------------------------------------------------------
// Single fused kernel. Block = (b, og): 4 output channels o = og*4..og*4+3.
// Grid 512 = 2 blocks/CU co-resident (LDS 46.8KB) -> 16 waves/CU.
// Rounds r = (side s = r>>1, k-half p = r&1): stage X/W bf16 in LDS,
//   GEMM S_s[m][n] (n = oo*9 + shift*3 + free; side-1 3x3 tap block transposed
//   in the staging scatter so shift tap = kw). Then S (f32, LDS) ->
//   shift-recombination -> gelu-mean -> residual writeout.
// ---------------------------------------------------------------------------
__global__ __launch_bounds__(512, 4) void tc_all(
    const float* __restrict__ x1, const float* __restrict__ x2,
    const float* __restrict__ W, const float* __restrict__ bias,
    const float* __restrict__ alpha_p, float* __restrict__ out)
{
    __shared__ __align__(16) char smem[SMEMB];
    ushort* Xs = (ushort*)smem;
    ushort* Ws = (ushort*)(smem + OFF_WS);
    float*  S0 = (float*)smem;
    float*  S1 = (float*)(smem + OFF_S1);
    float*  Bv = (float*)(smem + OFF_BV);
    float*  Lo = (float*)(smem + OFF_LO);

    const int u  = threadIdx.x;
    const int b  = blockIdx.x >> 6;
    const int og = blockIdx.x & 63;
    const int l  = u & 63, w = u >> 6;       // wave id 0..7
    const int r16 = l & 15, kb = l >> 4;

    const int xrow = u >> 2, xcb = (u & 3) * 32;
    const size_t xoff  = (size_t)(b * T_ + xrow) * C_ + xcb;
    const size_t wbase = (size_t)og * 4 * 4608;

    f32x4 acc[2][3] = {};
    ushort8v xbuf[2][4];
    ushort   wbuf[2][9];

    // zero Ws pad rows 36..47 (read by nf=2 frags, lanes n>=36 discarded later;
    // avoid reading uninitialized LDS)
    {
        int base = 36 * XLDP;
        for (int i = u; i < 12 * XLDP; i += 512) Ws[base + i] = 0;
    }

    // ---- preload round 0 (s=0, p=0)
    {
        const float* xs = x1 + xoff;
        #pragma unroll
        for (int c = 0; c < 4; ++c) {
            float4 lo = *(const float4*)(xs + c * 8);
            float4 hi = *(const float4*)(xs + c * 8 + 4);
            xbuf[0][c] = pack8(lo, hi);
        }
        #pragma unroll
        for (int i = 0; i < 9; ++i) {
            int d = i * 512 + u;                      // 0..4607
            int oo = d / 1152, e = d - oo * 1152;     // e = kk*9 + r9
            wbuf[0][i] = f2bf(W[wbase + (size_t)oo * 4608 + e]);
        }
    }

    #pragma unroll
    for (int r = 0; r < 4; ++r) {
        const int cur = r & 1;
        const int s   = r >> 1;
        __syncthreads();                     // prior round's frag reads done
        #pragma unroll
        for (int c = 0; c < 4; ++c)
            *(ushort8v*)&Xs[xrow * XLDP + xcb + c * 8] = xbuf[cur][c];
        #pragma unroll
        for (int i = 0; i < 9; ++i) {
            int d  = i * 512 + u;
            int oo = d / 1152, e = d - oo * 1152;
            int kk = e / 9,    r9 = e - kk * 9;
            int rd = (s == 0) ? r9 : (r9 % 3) * 3 + (r9 / 3);  // side-1 tap transpose
            Ws[(oo * 9 + rd) * XLDP + kk] = wbuf[cur][i];
        }
        if (r < 3) {                         // prefetch next round
            const int rn = r + 1, sn = rn >> 1, pn = rn & 1;
            const float* xs = (sn ? x2 : x1) + xoff + pn * 128;
            #pragma unroll
            for (int c = 0; c < 4; ++c) {
                float4 lo = *(const float4*)(xs + c * 8);
                float4 hi = *(const float4*)(xs + c * 8 + 4);
                xbuf[cur ^ 1][c] = pack8(lo, hi);
            }
            const int soff9 = (sn * 256 + pn * 128) * 9;
            #pragma unroll
            for (int i = 0; i < 9; ++i) {
                int d = i * 512 + u;
                int oo = d / 1152, e = d - oo * 1152;
                wbuf[cur ^ 1][i] = f2bf(W[wbase + (size_t)oo * 4608 + soff9 + e]);
            }
        }
        __syncthreads();
        // ---- MFMA: wave w owns m-rows w*16..w*16+15, 3 n-frags (48 cols, 36 used)
        #pragma unroll
        for (int ks = 0; ks < 4; ++ks) {
            bf16x8 af = __builtin_bit_cast(bf16x8,
                *(const ushort8v*)&Xs[(w * 16 + r16) * XLDP + ks * 32 + kb * 8]);
            #pragma unroll
            for (int nf = 0; nf < 3; ++nf) {
                bf16x8 bfr = __builtin_bit_cast(bf16x8,
                    *(const ushort8v*)&Ws[(nf * 16 + r16) * XLDP + ks * 32 + kb * 8]);
                acc[s][nf] = __builtin_amdgcn_mfma_f32_16x16x32_bf16(af, bfr, acc[s][nf], 0, 0, 0);
            }
        }
    }
    __syncthreads();                          // all frag reads done; reuse LDS for S

    // ---- write S (f32): D layout m = w*16 + kb*4 + reg, n = nf*16 + r16
    #pragma unroll
    for (int s = 0; s < 2; ++s) {
        float* Sb = s ? S1 : S0;
        #pragma unroll
        for (int nf = 0; nf < 3; ++nf) {
            int n = nf * 16 + r16;
            if (n < 36) {
                #pragma unroll
                for (int reg = 0; reg < 4; ++reg)
                    Sb[(w * 16 + kb * 4 + reg) * SLDW + n] = acc[s][nf][reg];
            }
        }
    }
    __syncthreads();

    // ---- recombination: thread u -> oo = u>>7 (0..3), t = u&127
    const int oo = u >> 7;
    const int t  = u & 127;
    const float bo = bias[og * 4 + oo];
    float a0 = 0.f, a1 = 0.f, a2 = 0.f;          // free tap = kw
    float b0 = 0.f, b1 = 0.f, b2 = 0.f;          // free tap = kh
    #pragma unroll
    for (int sh = 0; sh < 3; ++sh) {             // shift tap on own t axis
        int row = t + sh - 1;
        if (row >= 0 && row < T_) {
            int base = row * SLDW + oo * 9 + sh * 3;
            a0 += S0[base]; a1 += S0[base + 1]; a2 += S0[base + 2];
            b0 += S1[base]; b1 += S1[base + 1]; b2 += S1[base + 2];
        }
    }
    float A3 = bo + a0 + a1 + a2;                // interior t2
    float Al = bo + a1 + a2;                     // t2 == 0
    float Ar = bo + a0 + a1;                     // t2 == T-1
    Bv[(oo * 3 + 0) * T_ + t] = b0 + b1 + b2;    // interior t1
    Bv[(oo * 3 + 1) * T_ + t] = b1 + b2;         // t1 == 0
    Bv[(oo * 3 + 2) * T_ + t] = b0 + b1;         // t1 == T-1
    __syncthreads();

    // ---- gelu-mean: thread (oo, t1=t), 128 t2 evals
    {
        int cls = (t == 0) ? 1 : ((t == T_ - 1) ? 2 : 0);
        const float* Bs = Bv + (oo * 3 + cls) * T_;
        float s0 = 0.f, s1 = 0.f, s2 = 0.f, s3 = 0.f;
        for (int j = 0; j < T_; j += 4) {
            f32x4 v = *(const f32x4*)&Bs[j];
            s0 += gelu_fast(A3 + v[0]); s1 += gelu_fast(A3 + v[1]);
            s2 += gelu_fast(A3 + v[2]); s3 += gelu_fast(A3 + v[3]);
        }
        float sm = (s0 + s1) + (s2 + s3);
        float bl = Bs[0], br = Bs[T_ - 1];
        sm += gelu_fast(Al + bl) - gelu_fast(A3 + bl);
        sm += gelu_fast(Ar + br) - gelu_fast(A3 + br);
        Lo[t * LOP + oo] = sm;
    }
    __syncthreads();

    // ---- transposed coalesced writeout with residual
    const float kk2 = (*alpha_p) * (1.0f / (float)T_);
    {
        int row = u >> 2, c = u & 3;
        size_t go = ((size_t)(b * T_ + row)) * C_ + og * 4 + c;
        out[go] = Lo[row * LOP + c] * kk2 + x1[go];
    }
}

extern "C" void kernel_launch(void* const* d_in, const int* in_sizes, int n_in,
                              void* d_out, int out_size, void* d_ws, size_t ws_size,
                              hipStream_t stream) {
    const float* x1    = (const float*)d_in[0];
    const float* x2    = (const float*)d_in[1];
    const float* W     = (const float*)d_in[2];
    const float* bias  = (const float*)d_in[3];
    const float* alpha = (const float*)d_in[4];
    float* out = (float*)d_out;

    tc_all<<<B_ * 64, 512, 0, stream>>>(x1, x2, W, bias, alpha, out);
}

// Round 7
// 94.806 us; speedup vs baseline: 1.1312x; 1.0593x over previous
//
#include <hip/hip_runtime.h>
#include <math.h>

#define B_   8
#define T_   128
#define C_   256
#define XLDP 136       // LDS row stride in ushorts (128 + 8 pad)

typedef unsigned short ushort;
typedef ushort ushort8v __attribute__((ext_vector_type(8)));
typedef __bf16 bf16x8  __attribute__((ext_vector_type(8)));
typedef float  f32x4   __attribute__((ext_vector_type(4)));

__device__ __forceinline__ ushort f2bf(float f) {
    unsigned u = __float_as_uint(f);
    u += 0x7fffu + ((u >> 16) & 1u);     // RNE
    return (ushort)(u >> 16);
}

// gelu ~ x * sigmoid(1.59577x + 0.0713548x^3); exp2-folded, native v_exp_f32
__device__ __forceinline__ float gelu_fast(float x) {
    float x2 = x * x;
    float y2 = x * fmaf(-0.10294234f, x2, -2.30220818f);  // -y*log2(e)
    float e  = __builtin_amdgcn_exp2f(y2);
    return x * __builtin_amdgcn_rcpf(1.0f + e);
}

// ---------------------------------------------------------------------------
// Pack kernel.
//  blocks 0..255  : W pack, one block per o.
//    Wt[s][og=o>>2][ (o&3)*9 + rd ][ci]  (48-row padded per og; rows 36..47 unset)
//    s=0: rd = kh*3+kw holds W[o][ci][kh][kw]
//    s=1: rd = kw*3+kh holds W[o][256+ci][kh][kw]  (3x3 tap transpose)
//  blocks 256..511: X pack: Xp[s][m][k] bf16, m = b*128+t.
// ---------------------------------------------------------------------------
__global__ __launch_bounds__(256) void tc_pack(
    const float* __restrict__ x1, const float* __restrict__ x2,
    const float* __restrict__ W, ushort* __restrict__ Xp,
    ushort* __restrict__ Wt)
{
    const int bid = blockIdx.x, t = threadIdx.x;
    if (bid < 256) {                         // ---- W pack
        __shared__ ushort lw[4608];          // linear copy of W[o]: [ch512][r9]
        const float* src = W + (size_t)bid * 4608;
        #pragma unroll
        for (int i = 0; i < 18; ++i)
            lw[t + i * 256] = f2bf(src[t + i * 256]);
        __syncthreads();
        #pragma unroll
        for (int i = 0; i < 18; ++i) {
            int d = t + i * 256;             // 0..4607
            int c = d & 255;
            int row18 = d >> 8;              // s*9 + r
            int s = (row18 >= 9) ? 1 : 0;
            int r = row18 - s * 9;
            int rsrc = (s == 0) ? r : (r % 3) * 3 + (r / 3);
            Wt[(((size_t)s * 64 + (bid >> 2)) * 48 + (bid & 3) * 9 + r) * 256 + c]
                = lw[(s * 256 + c) * 9 + rsrc];
        }
    } else {                                 // ---- X pack
        int g = (bid - 256) * 256 + t;       // ushort8 chunk id
        int e = g * 8;
        int s  = e >> 18;
        int me = e & 262143;
        const float* src = (s ? x2 : x1) + me;
        float4 lo = *(const float4*)src;
        float4 hi = *(const float4*)(src + 4);
        ushort8v u;
        u[0] = f2bf(lo.x); u[1] = f2bf(lo.y); u[2] = f2bf(lo.z); u[3] = f2bf(lo.w);
        u[4] = f2bf(hi.x); u[5] = f2bf(hi.y); u[6] = f2bf(hi.z); u[7] = f2bf(hi.w);
        *(ushort8v*)&Xp[e] = u;
    }
}

// ---------------------------------------------------------------------------
// Pure GEMM: Sg[s][og*36+n][m] = sum_k Xp[s][m][k] * Wt[s][og][n][k]
// Block (og, mh): M=64 rows (mh*64..), N=48 (36 valid), K=256 over 4 rounds.
// 4 waves; clean b128 staging from pre-packed inputs; f32x4 reg->global S store.
// ---------------------------------------------------------------------------
__global__ __launch_bounds__(256, 4) void tc_gemm(
    const ushort* __restrict__ Xp, const ushort* __restrict__ Wt,
    float* __restrict__ Sg)
{
    __shared__ ushort Xs[64 * XLDP];
    __shared__ ushort Ws[48 * XLDP];

    const int og = blockIdx.x;           // 0..63
    const int mh = blockIdx.y;           // 0..15  (m block of 64)
    const int tid = threadIdx.x;
    const int l = tid & 63, w = tid >> 6;
    const int r16 = l & 15, kb = l >> 4;

    ushort8v xb[2][4], wb[2][3];
    f32x4 acc[2][3] = {};

    auto loadr = [&](int r, int buf) {
        int s = r >> 1, p = r & 1;
        const ushort* xsrc = Xp + ((size_t)s * 1024 + mh * 64) * 256 + p * 128;
        #pragma unroll
        for (int j = 0; j < 4; ++j) {
            int c = tid + j * 256;
            xb[buf][j] = *(const ushort8v*)(xsrc + (size_t)(c >> 4) * 256 + (c & 15) * 8);
        }
        const ushort* wsrc = Wt + ((size_t)s * 64 + og) * 48 * 256 + p * 128;
        #pragma unroll
        for (int j = 0; j < 3; ++j) {
            int c = tid + j * 256;
            wb[buf][j] = *(const ushort8v*)(wsrc + (size_t)(c >> 4) * 256 + (c & 15) * 8);
        }
    };

    loadr(0, 0);

    #pragma unroll
    for (int r = 0; r < 4; ++r) {
        const int cur = r & 1, s = r >> 1;
        __syncthreads();                 // prior round's frag reads done
        #pragma unroll
        for (int j = 0; j < 4; ++j) {
            int c = tid + j * 256;
            *(ushort8v*)&Xs[(c >> 4) * XLDP + (c & 15) * 8] = xb[cur][j];
        }
        #pragma unroll
        for (int j = 0; j < 3; ++j) {
            int c = tid + j * 256;
            *(ushort8v*)&Ws[(c >> 4) * XLDP + (c & 15) * 8] = wb[cur][j];
        }
        if (r < 3) loadr(r + 1, cur ^ 1);
        __syncthreads();
        #pragma unroll
        for (int ks = 0; ks < 4; ++ks) {
            bf16x8 af = __builtin_bit_cast(bf16x8,
                *(const ushort8v*)&Xs[(w * 16 + r16) * XLDP + ks * 32 + kb * 8]);
            #pragma unroll
            for (int nf = 0; nf < 3; ++nf) {
                bf16x8 bfr = __builtin_bit_cast(bf16x8,
                    *(const ushort8v*)&Ws[(nf * 16 + r16) * XLDP + ks * 32 + kb * 8]);
                acc[s][nf] = __builtin_amdgcn_mfma_f32_16x16x32_bf16(af, bfr, acc[s][nf], 0, 0, 0);
            }
        }
    }

    // ---- store S: D layout row(m) = kb*4+reg (reg m-contiguous!), col(n) = r16
    #pragma unroll
    for (int s = 0; s < 2; ++s)
        #pragma unroll
        for (int nf = 0; nf < 3; ++nf) {
            int n = nf * 16 + r16;
            if (n < 36)
                *(f32x4*)&Sg[((size_t)(s * 64 + og) * 36 + n) * 1024
                             + mh * 64 + w * 16 + kb * 4] = acc[s][nf];
        }
}

// ---------------------------------------------------------------------------
// Finalize: block (b, o), 128 threads = t. Coalesced Sg reads, recomb, gelu-mean.
//   a_j(t1) = sum_valid_sh Sg0[oo*9+sh*3+j][b*128 + t1+sh-1]   (j = kw class)
//   b_j(t2) = sum_valid_sh Sg1[oo*9+sh*3+j][b*128 + t2+sh-1]   (j = kh class)
// ---------------------------------------------------------------------------
__global__ __launch_bounds__(128) void tc_fin(
    const float* __restrict__ Sg, const float* __restrict__ x1,
    const float* __restrict__ bias, const float* __restrict__ alpha_p,
    float* __restrict__ out)
{
    const int o = blockIdx.x & 255;
    const int b = blockIdx.x >> 8;
    const int t = threadIdx.x;
    const int og = o >> 2, oo = o & 3;

    __shared__ float Bv[3][T_];

    const float* S0 = Sg + ((size_t)og * 36 + oo * 9) * 1024 + b * 128;
    const float* S1 = Sg + ((size_t)(64 + og) * 36 + oo * 9) * 1024 + b * 128;

    float a0 = 0.f, a1 = 0.f, a2 = 0.f;
    float b0 = 0.f, b1 = 0.f, b2 = 0.f;
    #pragma unroll
    for (int sh = 0; sh < 3; ++sh) {
        int row = t + sh - 1;
        if (row >= 0 && row < T_) {
            const float* p0 = S0 + sh * 3 * 1024 + row;
            a0 += p0[0]; a1 += p0[1024]; a2 += p0[2048];
            const float* p1 = S1 + sh * 3 * 1024 + row;
            b0 += p1[0]; b1 += p1[1024]; b2 += p1[2048];
        }
    }
    const float bo = bias[o];
    float A3 = bo + a0 + a1 + a2;                // interior t2
    float Al = bo + a1 + a2;                     // t2 == 0
    float Ar = bo + a0 + a1;                     // t2 == T-1
    Bv[0][t] = b0 + b1 + b2;                     // interior t1
    Bv[1][t] = b1 + b2;                          // t1 == 0
    Bv[2][t] = b0 + b1;                          // t1 == T-1
    __syncthreads();

    int cls = (t == 0) ? 1 : ((t == T_ - 1) ? 2 : 0);
    const float* Bs = Bv[cls];
    float s0 = 0.f, s1 = 0.f, s2 = 0.f, s3 = 0.f;
    for (int j = 0; j < T_; j += 4) {
        f32x4 v = *(const f32x4*)&Bs[j];
        s0 += gelu_fast(A3 + v[0]); s1 += gelu_fast(A3 + v[1]);
        s2 += gelu_fast(A3 + v[2]); s3 += gelu_fast(A3 + v[3]);
    }
    float sm = (s0 + s1) + (s2 + s3);
    float bl = Bs[0], br = Bs[T_ - 1];
    sm += gelu_fast(Al + bl) - gelu_fast(A3 + bl);
    sm += gelu_fast(Ar + br) - gelu_fast(A3 + br);

    const float kk2 = (*alpha_p) * (1.0f / (float)T_);
    size_t go = ((size_t)(b * T_ + t)) * C_ + o;
    out[go] = sm * kk2 + x1[go];
}

extern "C" void kernel_launch(void* const* d_in, const int* in_sizes, int n_in,
                              void* d_out, int out_size, void* d_ws, size_t ws_size,
                              hipStream_t stream) {
    const float* x1    = (const float*)d_in[0];
    const float* x2    = (const float*)d_in[1];
    const float* W     = (const float*)d_in[2];
    const float* bias  = (const float*)d_in[3];
    const float* alpha = (const float*)d_in[4];
    float* out = (float*)d_out;

    // ws: Sg f32 [2][64*36][1024] = 18.87 MB | Xp bf16 [2][1024][256] = 1.05 MB
    //   | Wt bf16 [2][64][48][256] = 3.15 MB
    float*  Sg = (float*)d_ws;
    ushort* Xp = (ushort*)((char*)d_ws + (size_t)2 * 64 * 36 * 1024 * 4);
    ushort* Wt = Xp + (size_t)2 * 1024 * 256;

    tc_pack<<<512, 256, 0, stream>>>(x1, x2, W, Xp, Wt);
    tc_gemm<<<dim3(64, 16), 256, 0, stream>>>(Xp, Wt, Sg);
    tc_fin<<<B_ * C_, T_, 0, stream>>>(Sg, x1, bias, alpha, out);
}

// Round 9
// 90.551 us; speedup vs baseline: 1.1844x; 1.0470x over previous
//
#include <hip/hip_runtime.h>
#include <math.h>

#define B_   8
#define T_   128
#define C_   256
#define XLDS 264       // Xs row stride in ushorts (256 data + 8 pad; 132 dw -> 2-way free)
#define WLDP 136       // Ws row stride in ushorts (128 data + 8 pad)

typedef unsigned short ushort;
typedef ushort ushort8v __attribute__((ext_vector_type(8)));
typedef __bf16 bf16x8  __attribute__((ext_vector_type(8)));
typedef float  f32x4   __attribute__((ext_vector_type(4)));

__device__ __forceinline__ ushort f2bf(float f) {
    unsigned u = __float_as_uint(f);
    u += 0x7fffu + ((u >> 16) & 1u);     // RNE
    return (ushort)(u >> 16);
}

// gelu ~ x * sigmoid(1.59577x + 0.0713548x^3); exp2-folded, native v_exp_f32
__device__ __forceinline__ float gelu_fast(float x) {
    float x2 = x * x;
    float y2 = x * fmaf(-0.10294234f, x2, -2.30220818f);  // -y*log2(e)
    float e  = __builtin_amdgcn_exp2f(y2);
    return x * __builtin_amdgcn_rcpf(1.0f + e);
}

// ---------------------------------------------------------------------------
// Pack kernel.
//  blocks 0..255  (one per o): Wt[2][768][768] bf16:
//    Wt[0][o*3+kw][kh*256+ci] = W[o][ci][kh][kw]
//    Wt[1][o*3+kh][kw*256+ci] = W[o][256+ci][kh][kw]
//  blocks 256..511: Xp[s][m][ci] bf16, m = b*128+t.
// ---------------------------------------------------------------------------
__global__ __launch_bounds__(256) void tc_pack(
    const float* __restrict__ x1, const float* __restrict__ x2,
    const float* __restrict__ W, ushort* __restrict__ Xp,
    ushort* __restrict__ Wt)
{
    const int bid = blockIdx.x, t = threadIdx.x;
    if (bid < 256) {                         // ---- W pack
        __shared__ ushort lw[4608];          // W[o] linear: [c 512][r 9]
        const float* src = W + (size_t)bid * 4608;
        #pragma unroll
        for (int i = 0; i < 18; ++i)
            lw[t + i * 256] = f2bf(src[t + i * 256]);
        __syncthreads();
        #pragma unroll
        for (int i = 0; i < 18; ++i) {
            int d  = t + i * 256;            // 0..4607
            int s  = d / 2304;
            int e  = d - s * 2304;
            int nj = e / 768;                // kw (s=0) / kh (s=1)
            int k  = e - nj * 768;           // sh*256 + ci
            int sh = k >> 8, ci = k & 255;
            ushort v = (s == 0) ? lw[ci * 9 + sh * 3 + nj]
                                : lw[(256 + ci) * 9 + nj * 3 + sh];
            Wt[((size_t)s * 768 + bid * 3 + nj) * 768 + k] = v;
        }
    } else {                                 // ---- X pack
        int g = (bid - 256) * 256 + t;       // ushort8 chunk id
        int e = g * 8;
        int s  = e >> 18;
        int me = e & 262143;
        const float* src = (s ? x2 : x1) + me;
        float4 lo = *(const float4*)src;
        float4 hi = *(const float4*)(src + 4);
        ushort8v u;
        u[0] = f2bf(lo.x); u[1] = f2bf(lo.y); u[2] = f2bf(lo.z); u[3] = f2bf(lo.w);
        u[4] = f2bf(hi.x); u[5] = f2bf(hi.y); u[6] = f2bf(hi.z); u[7] = f2bf(hi.w);
        *(ushort8v*)&Xp[e] = u;
    }
}

// ---------------------------------------------------------------------------
// Shift-fused GEMM: AB[s][n][m] = sum_sh sum_ci Xpad[s][m+sh-1][ci]*Wt[s][n][sh*256+ci]
// Block (tn 0..11, tm 0..15, s): M=64, N=64, K=768 as 6 rounds (sh x k-half).
// X staged ONCE as 66 rows x 256 k (stride 264; batch-boundary rows zeroed);
// the kh/kw shift = A-fragment row offset (+sh). W reg-prefetched per round.
// ---------------------------------------------------------------------------
__global__ __launch_bounds__(256, 3) void tc_gemm(
    const ushort* __restrict__ Xp, const ushort* __restrict__ Wt,
    float* __restrict__ AB)
{
    __shared__ ushort Xs[66 * XLDS];     // 34848 B
    __shared__ ushort Ws[64 * WLDP];     // 17408 B

    const int tn = blockIdx.x;           // 0..11
    const int tm = blockIdx.y;           // 0..15
    const int s  = blockIdx.z;
    const int u  = threadIdx.x;
    const int l  = u & 63, w = u >> 6;
    const int wr = w >> 1, wc = w & 1;
    const int r16 = l & 15, kb = l >> 4;

    const int b_     = tm >> 1;
    const int t_base = (tm & 1) * 64;
    const ushort* Xb = Xp + ((size_t)s * 1024 + b_ * T_) * C_;
    const ushort* Wb = Wt + ((size_t)s * 768 + tn * 64) * 768;

    // ---- stage X rows -1..64 (66 rows x 256 ci), zero out-of-batch rows
    {
        ushort8v zero = {};
        #pragma unroll
        for (int j = 0; j < 9; ++j) {
            int c = u + j * 256;
            if (j < 8 || c < 2112) {
                int i  = c >> 5;             // staged row 0..65
                int kc = (c & 31) * 8;
                int t  = t_base + i - 1;
                ushort8v v = (t >= 0 && t < T_)
                           ? *(const ushort8v*)(Xb + (size_t)t * C_ + kc) : zero;
                *(ushort8v*)&Xs[i * XLDS + kc] = v;
            }
        }
    }

    // ---- prefetch round 0 W tile (64 n x 128 k) into regs
    ushort8v wbuf[4];
    #pragma unroll
    for (int j = 0; j < 4; ++j) {
        int c = u + j * 256;
        wbuf[j] = *(const ushort8v*)(Wb + (size_t)(c >> 4) * 768 + (c & 15) * 8);
    }

    f32x4 acc[2][2] = {};
    #pragma unroll
    for (int r = 0; r < 6; ++r) {
        const int sh = r >> 1, p = r & 1;
        __syncthreads();                 // X staged / prior round's W frag reads done
        #pragma unroll
        for (int j = 0; j < 4; ++j) {
            int c = u + j * 256;
            *(ushort8v*)&Ws[(c >> 4) * WLDP + (c & 15) * 8] = wbuf[j];
        }
        if (r < 5) {
            const int rn = r + 1;
            const ushort* wsrc = Wb + (rn >> 1) * 256 + (rn & 1) * 128;
            #pragma unroll
            for (int j = 0; j < 4; ++j) {
                int c = u + j * 256;
                wbuf[j] = *(const ushort8v*)(wsrc + (size_t)(c >> 4) * 768 + (c & 15) * 8);
            }
        }
        __syncthreads();
        #pragma unroll
        for (int ks = 0; ks < 4; ++ks) {
            const int ka = p * 128 + ks * 32 + kb * 8;
            const int kw_ = ks * 32 + kb * 8;
            bf16x8 a0 = __builtin_bit_cast(bf16x8,
                *(const ushort8v*)&Xs[(wr * 32 + r16 + sh) * XLDS + ka]);
            bf16x8 a1 = __builtin_bit_cast(bf16x8,
                *(const ushort8v*)&Xs[(wr * 32 + 16 + r16 + sh) * XLDS + ka]);
            bf16x8 b0 = __builtin_bit_cast(bf16x8,
                *(const ushort8v*)&Ws[(wc * 32 + r16) * WLDP + kw_]);
            bf16x8 b1 = __builtin_bit_cast(bf16x8,
                *(const ushort8v*)&Ws[(wc * 32 + 16 + r16) * WLDP + kw_]);
            acc[0][0] = __builtin_amdgcn_mfma_f32_16x16x32_bf16(a0, b0, acc[0][0], 0, 0, 0);
            acc[0][1] = __builtin_amdgcn_mfma_f32_16x16x32_bf16(a0, b1, acc[0][1], 0, 0, 0);
            acc[1][0] = __builtin_amdgcn_mfma_f32_16x16x32_bf16(a1, b0, acc[1][0], 0, 0, 0);
            acc[1][1] = __builtin_amdgcn_mfma_f32_16x16x32_bf16(a1, b1, acc[1][1], 0, 0, 0);
        }
    }

    // ---- store AB[s][n][m]; D: col(n)=r16, row(m)=kb*4+reg (m-contiguous f32x4)
    #pragma unroll
    for (int j = 0; j < 2; ++j) {
        int n = tn * 64 + wc * 32 + j * 16 + r16;
        #pragma unroll
        for (int i = 0; i < 2; ++i) {
            int m = tm * 64 + wr * 32 + i * 16 + kb * 4;
            *(f32x4*)&AB[((size_t)s * 768 + n) * 1024 + m] = acc[i][j];
        }
    }
}

// ---------------------------------------------------------------------------
// Finalize: block (b, o), 128 threads = t.
//   a_j = AB[0][o*3+j][b*128+t]  (j = kw class; kh-shift folded in GEMM)
//   b_j = AB[1][o*3+j][b*128+t]  (j = kh class)
// ---------------------------------------------------------------------------
__global__ __launch_bounds__(128) void tc_fin(
    const float* __restrict__ AB, const float* __restrict__ x1,
    const float* __restrict__ bias, const float* __restrict__ alpha_p,
    float* __restrict__ out)
{
    const int o = blockIdx.x & 255;
    const int b = blockIdx.x >> 8;
    const int t = threadIdx.x;

    __shared__ float Bv[3][T_];

    const float* A0 = AB + ((size_t)o * 3) * 1024 + b * T_ + t;
    const float* A1 = AB + ((size_t)768 + o * 3) * 1024 + b * T_ + t;
    float a0 = A0[0], a1 = A0[1024], a2 = A0[2048];
    float b0 = A1[0], b1 = A1[1024], b2 = A1[2048];

    const float bo = bias[o];
    float A3 = bo + a0 + a1 + a2;                // interior t2
    float Al = bo + a1 + a2;                     // t2 == 0   (kw=0 invalid)
    float Ar = bo + a0 + a1;                     // t2 == T-1 (kw=2 invalid)
    Bv[0][t] = b0 + b1 + b2;                     // interior t1
    Bv[1][t] = b1 + b2;                          // t1 == 0   (kh=0 invalid)
    Bv[2][t] = b0 + b1;                          // t1 == T-1 (kh=2 invalid)
    __syncthreads();

    int cls = (t == 0) ? 1 : ((t == T_ - 1) ? 2 : 0);
    const float* Bs = Bv[cls];
    float s0 = 0.f, s1 = 0.f, s2 = 0.f, s3 = 0.f;
    for (int j = 0; j < T_; j += 4) {
        f32x4 v = *(const f32x4*)&Bs[j];
        s0 += gelu_fast(A3 + v[0]); s1 += gelu_fast(A3 + v[1]);
        s2 += gelu_fast(A3 + v[2]); s3 += gelu_fast(A3 + v[3]);
    }
    float sm = (s0 + s1) + (s2 + s3);
    float bl = Bs[0], br = Bs[T_ - 1];
    sm += gelu_fast(Al + bl) - gelu_fast(A3 + bl);
    sm += gelu_fast(Ar + br) - gelu_fast(A3 + br);

    const float kk2 = (*alpha_p) * (1.0f / (float)T_);
    size_t go = ((size_t)(b * T_ + t)) * C_ + o;
    out[go] = sm * kk2 + x1[go];
}

extern "C" void kernel_launch(void* const* d_in, const int* in_sizes, int n_in,
                              void* d_out, int out_size, void* d_ws, size_t ws_size,
                              hipStream_t stream) {
    const float* x1    = (const float*)d_in[0];
    const float* x2    = (const float*)d_in[1];
    const float* W     = (const float*)d_in[2];
    const float* bias  = (const float*)d_in[3];
    const float* alpha = (const float*)d_in[4];
    float* out = (float*)d_out;

    // ws: AB f32 [2][768][1024] = 6.29 MB | Xp bf16 [2][1024][256] = 1.05 MB
    //   | Wt bf16 [2][768][768] = 2.36 MB
    float*  AB = (float*)d_ws;
    ushort* Xp = (ushort*)((char*)d_ws + (size_t)2 * 768 * 1024 * 4);
    ushort* Wt = Xp + (size_t)2 * 1024 * 256;

    tc_pack<<<512, 256, 0, stream>>>(x1, x2, W, Xp, Wt);
    tc_gemm<<<dim3(12, 16, 2), 256, 0, stream>>>(Xp, Wt, AB);
    tc_fin<<<B_ * C_, T_, 0, stream>>>(AB, x1, bias, alpha, out);
}